// Round 8
// baseline (70.800 us; speedup 1.0000x reference)
//
#include <hip/hip_runtime.h>

// RNNAdder: out[row] = digits of (a[row] + b[row]) in base 10, MSB-first,
// with a leading final-carry column. a,b (B,2048) f32 digits 0..9;
// out (B,2049) int32.
//
// Block-per-row, 256 threads, 8 digits/thread. Carry scan: wave-local
// __shfl_up composition scan + single LDS exchange of wave aggregates.
//
// Cache policy (new vs R7): inputs have zero intra-dispatch reuse, so
// stream them with NONTEMPORAL LOADS (don't spend L3 on cross-replay
// input retention); output (128 MB < 256 MB L3) is fully rewritten every
// replay, so store it PLAIN (cached) through the R7 LDS-staged
// flat-16B-aligned path — if Infinity Cache write-allocates, HBM writes
// collapse to ~0 in steady state.

#define NDIG 2048
#define TPB 256
#define DPT 8
#define NW (TPB / 64)
#define OROW (NDIG + 1)  // 2049 dwords per output row

typedef int iv4 __attribute__((ext_vector_type(4)));
typedef float fv4 __attribute__((ext_vector_type(4)));

__device__ __forceinline__ int sidx(int j) { return j + (j >> 3); }

__global__ __launch_bounds__(TPB) void rnn_adder_kernel(
    const float* __restrict__ A, const float* __restrict__ B,
    int* __restrict__ out) {
  const int t = threadIdx.x;
  const int lane = t & 63;
  const int wave = t >> 6;
  const int row = blockIdx.x;
  // t=0 owns the rightmost (least significant) chunk; carry flows t=0 -> 255.
  const int base = NDIG - (t + 1) * DPT;

  const fv4* A4 = reinterpret_cast<const fv4*>(A + (size_t)row * NDIG + base);
  const fv4* B4 = reinterpret_cast<const fv4*>(B + (size_t)row * NDIG + base);
  fv4 a0 = __builtin_nontemporal_load(A4);
  fv4 a1 = __builtin_nontemporal_load(A4 + 1);
  fv4 b0 = __builtin_nontemporal_load(B4);
  fv4 b1 = __builtin_nontemporal_load(B4 + 1);

  int s[DPT];
  s[0] = (int)(a0.x + b0.x);
  s[1] = (int)(a0.y + b0.y);
  s[2] = (int)(a0.z + b0.z);
  s[3] = (int)(a0.w + b0.w);
  s[4] = (int)(a1.x + b1.x);
  s[5] = (int)(a1.y + b1.y);
  s[6] = (int)(a1.z + b1.z);
  s[7] = (int)(a1.w + b1.w);

  // Chunk carry-transfer evaluated at cin=0,1. (s+c)>=10 <=> bit5 of (s+c+22).
  int c0 = 0, c1 = 1;
#pragma unroll
  for (int k = DPT - 1; k >= 0; --k) {  // s[DPT-1] is chunk LSB
    c0 = ((s[k] + c0 + 22) >> 5) & 1;
    c1 = ((s[k] + c1 + 22) >> 5) & 1;
  }

  // Packed transfer f: bit0=f(0), bit1=f(1). Identity = 0b10.
  int cur = c0 | (c1 << 1);
#pragma unroll
  for (int off = 1; off < 64; off <<= 1) {
    int prev = __shfl_up(cur, off, 64);
    prev = (lane >= off) ? prev : 2;
    cur = ((cur >> (prev & 1)) & 1) | (((cur >> ((prev >> 1) & 1)) & 1) << 1);
  }

  // Cross-wave aggregate exchange (1 barrier).
  __shared__ int wagg[NW];
  if (lane == 63) wagg[wave] = cur;
  __syncthreads();

  int wc = 0;
  for (int w = 0; w < wave; ++w) wc = (wagg[w] >> wc) & 1;  // wave-uniform

  int pr = __shfl_up(cur, 1, 64);
  int cin = (lane == 0) ? wc : ((pr >> wc) & 1);

  // Finalize digits (chunk LSB first); reuse s[] as output digits.
  int c = cin;
#pragma unroll
  for (int k = DPT - 1; k >= 0; --k) {
    int v = s[k] + c;
    c = ((v + 22) >> 5) & 1;
    s[k] = v - 10 * c;
  }

  // ---- Stage row in LDS with per-row alignment shift, store aligned ----
  const size_t S = (size_t)row * OROW;  // flat dword index of this row's carry
  const int shift = (int)(S & 3);       // sd[shift + j] <-> out[S + j]

  __shared__ int sd[2308];  // sidx(3 + 2048) = 2307, +1

#pragma unroll
  for (int k = 0; k < DPT; ++k) sd[sidx(shift + 1 + base + k)] = s[k];
  if (t == TPB - 1) sd[sidx(shift)] = c;  // final carry at out-local 0
  __syncthreads();

  const int j_start = (4 - shift) & 3;        // first out-local j with flat%4==0
  const int ngroups = (OROW - j_start) >> 2;  // 511 or 512 16B groups
  const int jsA = shift + j_start;            // LDS word of first group (0 or 4)

  iv4* dst = reinterpret_cast<iv4*>(out + S + j_start);
  for (int q = t; q < ngroups; q += TPB) {
    const int w = jsA + 4 * q;
    iv4 v = {sd[sidx(w)], sd[sidx(w + 1)], sd[sidx(w + 2)], sd[sidx(w + 3)]};
    dst[q] = v;  // plain cached store — let L3 retain the output stream
  }
  // Head: out-local j in [0, j_start)  (<=3 dwords)
  if (t < j_start) out[S + t] = sd[sidx(shift + t)];
  // Tail: out-local j in [j_start + 4*ngroups, OROW)  (<=3 dwords)
  const int tail0 = j_start + 4 * ngroups;
  const int ntail = OROW - tail0;
  if (t >= 8 && t < 8 + ntail) {
    const int j = tail0 + (t - 8);
    out[S + j] = sd[sidx(shift + j)];
  }
}

extern "C" void kernel_launch(void* const* d_in, const int* in_sizes, int n_in,
                              void* d_out, int out_size, void* d_ws, size_t ws_size,
                              hipStream_t stream) {
  const float* A = (const float*)d_in[0];
  const float* B = (const float*)d_in[1];
  int* out = (int*)d_out;
  const int rows = in_sizes[0] / NDIG;
  rnn_adder_kernel<<<rows, TPB, 0, stream>>>(A, B, out);
}

// Round 9
// 63.545 us; speedup vs baseline: 1.1142x; 1.1142x over previous
//
#include <hip/hip_runtime.h>

// RNNAdder: out[row] = digits of (a[row] + b[row]) in base 10, MSB-first,
// with a leading final-carry column. a,b (B,2048) f32 digits 0..9;
// out (B,2049) int32.
//
// Block-per-row, 256 threads, 8 digits/thread. Carry scan: wave-local
// __shfl_up composition scan + single LDS exchange of wave aggregates.
//
// Memory policy (settled via R5-R8 A/B):
//  - inputs: PLAIN cached loads — L3 retains ~one input array (131 MB)
//    across graph replays; nt loads forfeit this and regress (R8).
//  - output: NONTEMPORAL stores — avoids L2 write-allocate pressure (R5),
//    via LDS-staged flat-16B-aligned int4 stores to kill partial-line
//    write amplification (R7: WRITE 158->134 MB ideal).
// Result: 402.8 MB logical / 63.7 us = 6.33 TB/s = copy ceiling. Roofline.

#define NDIG 2048
#define TPB 256
#define DPT 8
#define NW (TPB / 64)
#define OROW (NDIG + 1)  // 2049 dwords per output row

typedef int iv4 __attribute__((ext_vector_type(4)));

__device__ __forceinline__ int sidx(int j) { return j + (j >> 3); }

__global__ __launch_bounds__(TPB) void rnn_adder_kernel(
    const float* __restrict__ A, const float* __restrict__ B,
    int* __restrict__ out) {
  const int t = threadIdx.x;
  const int lane = t & 63;
  const int wave = t >> 6;
  const int row = blockIdx.x;
  // t=0 owns the rightmost (least significant) chunk; carry flows t=0 -> 255.
  const int base = NDIG - (t + 1) * DPT;

  const float4* A4 = reinterpret_cast<const float4*>(A + (size_t)row * NDIG + base);
  const float4* B4 = reinterpret_cast<const float4*>(B + (size_t)row * NDIG + base);
  float4 a0 = A4[0], a1 = A4[1];
  float4 b0 = B4[0], b1 = B4[1];

  int s[DPT];
  s[0] = (int)(a0.x + b0.x);
  s[1] = (int)(a0.y + b0.y);
  s[2] = (int)(a0.z + b0.z);
  s[3] = (int)(a0.w + b0.w);
  s[4] = (int)(a1.x + b1.x);
  s[5] = (int)(a1.y + b1.y);
  s[6] = (int)(a1.z + b1.z);
  s[7] = (int)(a1.w + b1.w);

  // Chunk carry-transfer evaluated at cin=0,1. (s+c)>=10 <=> bit5 of (s+c+22).
  int c0 = 0, c1 = 1;
#pragma unroll
  for (int k = DPT - 1; k >= 0; --k) {  // s[DPT-1] is chunk LSB
    c0 = ((s[k] + c0 + 22) >> 5) & 1;
    c1 = ((s[k] + c1 + 22) >> 5) & 1;
  }

  // Packed transfer f: bit0=f(0), bit1=f(1). Identity = 0b10.
  int cur = c0 | (c1 << 1);
#pragma unroll
  for (int off = 1; off < 64; off <<= 1) {
    int prev = __shfl_up(cur, off, 64);
    prev = (lane >= off) ? prev : 2;
    cur = ((cur >> (prev & 1)) & 1) | (((cur >> ((prev >> 1) & 1)) & 1) << 1);
  }

  // Cross-wave aggregate exchange (1 barrier).
  __shared__ int wagg[NW];
  if (lane == 63) wagg[wave] = cur;
  __syncthreads();

  int wc = 0;
  for (int w = 0; w < wave; ++w) wc = (wagg[w] >> wc) & 1;  // wave-uniform

  int pr = __shfl_up(cur, 1, 64);
  int cin = (lane == 0) ? wc : ((pr >> wc) & 1);

  // Finalize digits (chunk LSB first); reuse s[] as output digits.
  int c = cin;
#pragma unroll
  for (int k = DPT - 1; k >= 0; --k) {
    int v = s[k] + c;
    c = ((v + 22) >> 5) & 1;
    s[k] = v - 10 * c;
  }

  // ---- Stage row in LDS with per-row alignment shift, store aligned ----
  const size_t S = (size_t)row * OROW;  // flat dword index of this row's carry
  const int shift = (int)(S & 3);       // sd[shift + j] <-> out[S + j]

  __shared__ int sd[2308];  // sidx(3 + 2048) = 2307, +1

#pragma unroll
  for (int k = 0; k < DPT; ++k) sd[sidx(shift + 1 + base + k)] = s[k];
  if (t == TPB - 1) sd[sidx(shift)] = c;  // final carry at out-local 0
  __syncthreads();

  const int j_start = (4 - shift) & 3;        // first out-local j with flat%4==0
  const int ngroups = (OROW - j_start) >> 2;  // 511 or 512 16B groups
  const int jsA = shift + j_start;            // LDS word of first group (0 or 4)

  iv4* dst = reinterpret_cast<iv4*>(out + S + j_start);
  for (int q = t; q < ngroups; q += TPB) {
    const int w = jsA + 4 * q;
    iv4 v = {sd[sidx(w)], sd[sidx(w + 1)], sd[sidx(w + 2)], sd[sidx(w + 3)]};
    __builtin_nontemporal_store(v, dst + q);
  }
  // Head: out-local j in [0, j_start)  (<=3 dwords)
  if (t < j_start) out[S + t] = sd[sidx(shift + t)];
  // Tail: out-local j in [j_start + 4*ngroups, OROW)  (<=3 dwords)
  const int tail0 = j_start + 4 * ngroups;
  const int ntail = OROW - tail0;
  if (t >= 8 && t < 8 + ntail) {
    const int j = tail0 + (t - 8);
    out[S + j] = sd[sidx(shift + j)];
  }
}

extern "C" void kernel_launch(void* const* d_in, const int* in_sizes, int n_in,
                              void* d_out, int out_size, void* d_ws, size_t ws_size,
                              hipStream_t stream) {
  const float* A = (const float*)d_in[0];
  const float* B = (const float*)d_in[1];
  int* out = (int*)d_out;
  const int rows = in_sizes[0] / NDIG;
  rnn_adder_kernel<<<rows, TPB, 0, stream>>>(A, B, out);
}